// Round 2
// baseline (877.369 us; speedup 1.0000x reference)
//
#include <hip/hip_runtime.h>
#include <hip/hip_bf16.h>

typedef __attribute__((ext_vector_type(8))) __bf16 bf16x8;
typedef __attribute__((ext_vector_type(4))) float floatx4;

#define DEV static __device__ __forceinline__

DEV unsigned short f2bf(float f) {
  unsigned int u = __float_as_uint(f);
  u += 0x7fffu + ((u >> 16) & 1u);   // round-to-nearest-even
  return (unsigned short)(u >> 16);
}

DEV float wred_sum(float v) {
#pragma unroll
  for (int o = 32; o > 0; o >>= 1) v += __shfl_xor(v, o, 64);
  return v;
}

// ---------------- K1: emb = silu(t_emb) @ W_ada^T + b_ada  -> [2][4096] f32
__global__ void ada_kernel(const float* __restrict__ t_emb, const float* __restrict__ W_ada,
                           const float* __restrict__ b_ada, float* __restrict__ emb) {
  int w = threadIdx.x >> 6, lane = threadIdx.x & 63;
  int gid = blockIdx.x * 4 + w;          // 0..8191
  int b = gid >> 12, n = gid & 4095;
  const float* te = t_emb + (size_t)b * 1280;
  const float* wr = W_ada + (size_t)n * 1280;
  float acc = 0.f;
#pragma unroll
  for (int i = 0; i < 20; ++i) {
    int t = lane + i * 64;
    float x = te[t];
    float s = x / (1.f + __expf(-x));
    acc += s * wr[t];
  }
  acc = wred_sum(acc);
  if (lane == 0) emb[gid] = acc + b_ada[n];
}

// ---------------- K2: LayerNorm(ip) * (1+scale) + shift -> bf16 ip_n [1024][2048]
__global__ void ln_mod_kernel(const float* __restrict__ ip, const float* __restrict__ emb,
                              unsigned short* __restrict__ ipn) {
  int row = blockIdx.x;            // b*512 + l
  int b = row >> 9;
  const float* x = ip + (size_t)row * 2048;
  float xv[8];
  float s1 = 0.f, s2 = 0.f;
#pragma unroll
  for (int i = 0; i < 8; ++i) {
    float v = x[threadIdx.x + i * 256];
    xv[i] = v; s1 += v; s2 += v * v;
  }
  s1 = wred_sum(s1); s2 = wred_sum(s2);
  __shared__ float r1[4], r2[4];
  int w = threadIdx.x >> 6, lane = threadIdx.x & 63;
  if (lane == 0) { r1[w] = s1; r2[w] = s2; }
  __syncthreads();
  s1 = r1[0] + r1[1] + r1[2] + r1[3];
  s2 = r2[0] + r2[1] + r2[2] + r2[3];
  float mu = s1 * (1.f / 2048.f);
  float var = s2 * (1.f / 2048.f) - mu * mu;
  float rs = rsqrtf(var + 1e-6f);
  const float* sh = emb + (size_t)b * 4096;
  unsigned short* y = ipn + (size_t)row * 2048;
#pragma unroll
  for (int i = 0; i < 8; ++i) {
    int d = threadIdx.x + i * 256;
    float v = (xv[i] - mu) * rs;
    v = v * (1.f + sh[2048 + d]) + sh[d];
    y[d] = f2bf(v);
  }
}

// ---------------- K3: convert W_k_ip / W_v_ip fp32 -> bf16
struct us4 { unsigned short a, b, c, d; };
__global__ void cvtw_kernel(const float* __restrict__ wk, const float* __restrict__ wv,
                            unsigned short* __restrict__ wk16, unsigned short* __restrict__ wv16) {
  size_t i = ((size_t)blockIdx.x * 256 + threadIdx.x) * 4;
  float4 a = *(const float4*)(wk + i);
  float4 b = *(const float4*)(wv + i);
  us4 oa = { f2bf(a.x), f2bf(a.y), f2bf(a.z), f2bf(a.w) };
  us4 ob = { f2bf(b.x), f2bf(b.y), f2bf(b.z), f2bf(b.w) };
  *(us4*)(wk16 + i) = oa;
  *(us4*)(wv16 + i) = ob;
}

// ---------------- K4: C[1024,2048] = A[1024,2048]bf16 @ W[2048,2048]^T bf16 -> f32
// 128x64 tiles -> 512 blocks = 2/CU for latency overlap.
__global__ __launch_bounds__(256) void proj_gemm(const unsigned short* __restrict__ A,
    const unsigned short* __restrict__ Wk, const unsigned short* __restrict__ Wv,
    float* __restrict__ Ck, float* __restrict__ Cv) {
  const unsigned short* Bm = blockIdx.z ? Wv : Wk;
  float* C = blockIdx.z ? Cv : Ck;
  int n0 = blockIdx.x * 64, m0 = blockIdx.y * 128;
  __shared__ __align__(16) unsigned short As[128 * 72];
  __shared__ __align__(16) unsigned short Bs[64 * 72];
  int tid = threadIdx.x, w = tid >> 6, lane = tid & 63, quad = lane >> 4, l16 = lane & 15;
  floatx4 acc[2][4];
#pragma unroll
  for (int i = 0; i < 2; ++i)
#pragma unroll
    for (int j = 0; j < 4; ++j) { floatx4 z = {0.f, 0.f, 0.f, 0.f}; acc[i][j] = z; }
  for (int kk = 0; kk < 2048; kk += 64) {
#pragma unroll
    for (int it = 0; it < 4; ++it) {
      int idx = tid + it * 256;
      int row = idx >> 3, chk = idx & 7;
      *(uint4*)&As[row * 72 + chk * 8] = *(const uint4*)&A[(size_t)(m0 + row) * 2048 + kk + chk * 8];
    }
#pragma unroll
    for (int it = 0; it < 2; ++it) {
      int idx = tid + it * 256;
      int row = idx >> 3, chk = idx & 7;
      *(uint4*)&Bs[row * 72 + chk * 8] = *(const uint4*)&Bm[(size_t)(n0 + row) * 2048 + kk + chk * 8];
    }
    __syncthreads();
#pragma unroll
    for (int c = 0; c < 2; ++c) {
      bf16x8 a0 = *(const bf16x8*)&As[(w * 32 + l16) * 72 + quad * 8 + c * 32];
      bf16x8 a1 = *(const bf16x8*)&As[(w * 32 + 16 + l16) * 72 + quad * 8 + c * 32];
#pragma unroll
      for (int nt = 0; nt < 4; ++nt) {
        bf16x8 bb = *(const bf16x8*)&Bs[(nt * 16 + l16) * 72 + quad * 8 + c * 32];
        acc[0][nt] = __builtin_amdgcn_mfma_f32_16x16x32_bf16(a0, bb, acc[0][nt], 0, 0, 0);
        acc[1][nt] = __builtin_amdgcn_mfma_f32_16x16x32_bf16(a1, bb, acc[1][nt], 0, 0, 0);
      }
    }
    __syncthreads();
  }
#pragma unroll
  for (int rt = 0; rt < 2; ++rt)
#pragma unroll
    for (int nt = 0; nt < 4; ++nt)
#pragma unroll
      for (int r = 0; r < 4; ++r)
        C[(size_t)(m0 + w * 32 + rt * 16 + quad * 4 + r) * 2048 + n0 + nt * 16 + l16] = acc[rt][nt][r];
}

// ---------------- K5: build Kcat [bh][2560][128] bf16 (rms) and V^T [bh][128][2560] bf16
__global__ __launch_bounds__(256) void kv_build(const float* __restrict__ img_key, const float* __restrict__ img_value,
                         const float* __restrict__ ipk, const float* __restrict__ ipv,
                         const float* __restrict__ w_k, const float* __restrict__ w_ipk,
                         unsigned short* __restrict__ Kc, unsigned short* __restrict__ Vt) {
  int bh = blockIdx.x;                 // 0..31
  int mt = blockIdx.y;                 // 0..39
  int b = bh >> 4, hh = bh & 15;
  int m0 = mt * 64;
  __shared__ __align__(16) unsigned short Vs[64 * 132];
  int tid = threadIdx.x;
  int mrow = tid >> 2, dq = tid & 3;   // 64 rows x 4 quarters of d
  int m = m0 + mrow;
  size_t base;
  const float* wsrc;
  const float *ksrc, *vsrc;
  if (m < 2048) {
    base = (size_t)(b * 2048 + m) * 2048 + hh * 128;
    ksrc = img_key + base; vsrc = img_value + base; wsrc = w_k;
  } else {
    base = (size_t)(b * 512 + (m - 2048)) * 2048 + hh * 128;
    ksrc = ipk + base; vsrc = ipv + base; wsrc = w_ipk;
  }
  // K: load 32 d-values, rms over the 4 lanes sharing a row, write bf16
  float kvv[32]; float ss = 0.f;
  const float4* k4 = (const float4*)ksrc;
#pragma unroll
  for (int i = 0; i < 8; ++i) {
    float4 x = k4[dq * 8 + i];
    kvv[i * 4 + 0] = x.x; kvv[i * 4 + 1] = x.y; kvv[i * 4 + 2] = x.z; kvv[i * 4 + 3] = x.w;
    ss += x.x * x.x + x.y * x.y + x.z * x.z + x.w * x.w;
  }
  ss += __shfl_xor(ss, 1, 64);
  ss += __shfl_xor(ss, 2, 64);
  float rs = rsqrtf(ss * (1.f / 128.f) + 1e-6f);
  unsigned short kb[32];
#pragma unroll
  for (int j = 0; j < 32; ++j) kb[j] = f2bf(kvv[j] * rs * wsrc[dq * 32 + j]);
  uint4* kdst = (uint4*)&Kc[((size_t)bh * 2560 + m) * 128 + dq * 32];
#pragma unroll
  for (int i = 0; i < 4; ++i) kdst[i] = ((const uint4*)kb)[i];
  // V: to LDS as bf16 [m][d] (stride 132 to break conflicts), then transposed out
  const float4* v4 = (const float4*)vsrc;
#pragma unroll
  for (int i = 0; i < 8; ++i) {
    float4 x = v4[dq * 8 + i];
    us4 p = { f2bf(x.x), f2bf(x.y), f2bf(x.z), f2bf(x.w) };
    *(us4*)&Vs[mrow * 132 + dq * 32 + i * 4] = p;
  }
  __syncthreads();
  int d = tid >> 1, half = tid & 1;
  unsigned short ob[32];
#pragma unroll
  for (int j = 0; j < 32; ++j) ob[j] = Vs[(half * 32 + j) * 132 + d];
  uint4* vdst = (uint4*)&Vt[((size_t)bh * 128 + d) * 2560 + m0 + half * 32];
#pragma unroll
  for (int i = 0; i < 4; ++i) vdst[i] = ((const uint4*)ob)[i];
}

// ---------------- K6: Qn [B,H,2048,128] bf16 with rms
__global__ void q_build(const float* __restrict__ img_query, const float* __restrict__ w_q,
                        unsigned short* __restrict__ Qn) {
  int gid = blockIdx.x;                       // ((b*16+h)*2048 + l)
  int l = gid & 2047, hh = (gid >> 11) & 15, b = gid >> 15;
  int d = threadIdx.x;
  float qv = img_query[((size_t)(b * 2048 + l)) * 2048 + hh * 128 + d];
  float ss = wred_sum(qv * qv);
  __shared__ float red[2];
  if ((threadIdx.x & 63) == 0) red[threadIdx.x >> 6] = ss;
  __syncthreads();
  float tot = red[0] + red[1];
  float rs = rsqrtf(tot * (1.f / 128.f) + 1e-6f);
  Qn[(size_t)gid * 128 + d] = f2bf(qv * rs * w_q[d]);
}

// ---------------- K7: flash attention, barrier-free K-loop.
// K/V B-fragments loaded directly global->VGPR (L1/L2 serve reuse);
// fixed-max softmax (scores bounded: rms-normed q,k -> |s*log2e/sqrt(128)| <= 16.4);
// per-wave P roundtrip through LDS (no __syncthreads in the loop).
__global__ __launch_bounds__(256, 2) void attn_kernel(const unsigned short* __restrict__ Qn,
    const unsigned short* __restrict__ Kc, const unsigned short* __restrict__ Vt,
    float* __restrict__ out) {
  const float SCL = 0.12751744f;   // (1/sqrt(128)) * log2(e)
  const float FM = 17.0f;          // fixed softmax max (upper bound of s*SCL)
  int bh = blockIdx.x >> 5;        // b*16+h
  int qt = blockIdx.x & 31;
  int b = bh >> 4, hh = bh & 15;
  int tid = threadIdx.x, w = tid >> 6, lane = tid & 63, quad = lane >> 4, l16 = lane & 15;

  __shared__ __align__(16) unsigned short Pt[4 * 16 * 72];
  unsigned short* Pw = Pt + w * (16 * 72);

  int q0 = qt * 64;
  const unsigned short* Qbase = Qn + ((size_t)bh * 2048 + q0) * 128;
  const unsigned short* Kb = Kc + (size_t)bh * 2560 * 128;
  const unsigned short* Vb = Vt + (size_t)bh * 128 * 2560;

  bf16x8 aq[4];
  {
    int qrow = w * 16 + l16;
#pragma unroll
    for (int c = 0; c < 4; ++c)
      aq[c] = *(const bf16x8*)&Qbase[(size_t)qrow * 128 + quad * 8 + c * 32];
  }

  floatx4 acc[8];
#pragma unroll
  for (int i = 0; i < 8; ++i) { floatx4 z = {0.f, 0.f, 0.f, 0.f}; acc[i] = z; }
  float rsum[4] = {0.f, 0.f, 0.f, 0.f};

  for (int t = 0; t < 40; ++t) {
    const unsigned short* Kt = Kb + (size_t)t * 64 * 128;
    const unsigned short* Vtt = Vb + t * 64;
    // S = Q K^T : B-frags straight from global (contiguous in d)
    floatx4 s[4];
#pragma unroll
    for (int nt = 0; nt < 4; ++nt) {
      floatx4 z = {0.f, 0.f, 0.f, 0.f}; s[nt] = z;
#pragma unroll
      for (int c = 0; c < 4; ++c) {
        bf16x8 bk = *(const bf16x8*)&Kt[(size_t)(nt * 16 + l16) * 128 + quad * 8 + c * 32];
        s[nt] = __builtin_amdgcn_mfma_f32_16x16x32_bf16(aq[c], bk, s[nt], 0, 0, 0);
      }
    }
    // P = exp2(s*SCL - FM); per-lane partial row sums (reduced once at the end)
#pragma unroll
    for (int nt = 0; nt < 4; ++nt)
#pragma unroll
      for (int r = 0; r < 4; ++r) {
        float p = exp2f(s[nt][r] * SCL - FM);
        rsum[r] += p;
        Pw[(quad * 4 + r) * 72 + nt * 16 + l16] = f2bf(p);
      }
    // A-frag of P (wave-local LDS; DS ops are in-order per wave, no barrier)
    bf16x8 ap0 = *(const bf16x8*)&Pw[l16 * 72 + quad * 8];
    bf16x8 ap1 = *(const bf16x8*)&Pw[l16 * 72 + quad * 8 + 32];
    // O += P V : B-frags straight from global V^T (contiguous in m)
#pragma unroll
    for (int nt = 0; nt < 8; ++nt) {
      bf16x8 bv0 = *(const bf16x8*)&Vtt[(size_t)(nt * 16 + l16) * 2560 + quad * 8];
      bf16x8 bv1 = *(const bf16x8*)&Vtt[(size_t)(nt * 16 + l16) * 2560 + quad * 8 + 32];
      acc[nt] = __builtin_amdgcn_mfma_f32_16x16x32_bf16(ap0, bv0, acc[nt], 0, 0, 0);
      acc[nt] = __builtin_amdgcn_mfma_f32_16x16x32_bf16(ap1, bv1, acc[nt], 0, 0, 0);
    }
  }
  // final row-sum across the 16 l16 lanes
#pragma unroll
  for (int r = 0; r < 4; ++r) {
#pragma unroll
    for (int o = 1; o < 16; o <<= 1) rsum[r] += __shfl_xor(rsum[r], o, 64);
  }
  float inv[4];
#pragma unroll
  for (int r = 0; r < 4; ++r) inv[r] = 1.f / rsum[r];
#pragma unroll
  for (int nt = 0; nt < 8; ++nt)
#pragma unroll
    for (int r = 0; r < 4; ++r) {
      int qrow = q0 + w * 16 + quad * 4 + r;
      out[((size_t)(b * 2048 + qrow)) * 2048 + hh * 128 + nt * 16 + l16] = acc[nt][r] * inv[r];
    }
}

extern "C" void kernel_launch(void* const* d_in, const int* in_sizes, int n_in,
                              void* d_out, int out_size, void* d_ws, size_t ws_size,
                              hipStream_t stream) {
  const float* ip    = (const float*)d_in[0];
  const float* q     = (const float*)d_in[1];
  const float* k     = (const float*)d_in[2];
  const float* v     = (const float*)d_in[3];
  const float* temb  = (const float*)d_in[4];
  const float* wada  = (const float*)d_in[5];
  const float* bada  = (const float*)d_in[6];
  const float* wkip  = (const float*)d_in[7];
  const float* wvip  = (const float*)d_in[8];
  const float* w_q   = (const float*)d_in[9];
  const float* w_k   = (const float*)d_in[10];
  const float* w_ipk = (const float*)d_in[11];
  float* out = (float*)d_out;
  char* ws = (char*)d_ws;

  // Lifetime-overlapped workspace layout (75.5 MB total):
  //   emb[0,32K) ipn[32K,4.2M) wk16[4.2M,12.6M) wv16[12.6M,21.0M)  (dead after proj_gemm)
  //   Qn[0,16.7M) Kcat[16.7M,37.7M) Vt[37.7M,58.7M)                (written after proj_gemm)
  //   ipk[58.7M,67.1M) ipv[67.1M,75.5M)
  float* emb           = (float*)(ws + 0);
  unsigned short* ipn  = (unsigned short*)(ws + 32768);
  unsigned short* wk16 = (unsigned short*)(ws + 4227072);
  unsigned short* wv16 = (unsigned short*)(ws + 12615680);
  unsigned short* Qn   = (unsigned short*)(ws + 0);
  unsigned short* Kcat = (unsigned short*)(ws + 16777216);
  unsigned short* Vt   = (unsigned short*)(ws + 37748736);
  float* ipk           = (float*)(ws + 58720256);
  float* ipv           = (float*)(ws + 67108864);

  ada_kernel<<<dim3(2048), dim3(256), 0, stream>>>(temb, wada, bada, emb);
  ln_mod_kernel<<<dim3(1024), dim3(256), 0, stream>>>(ip, emb, ipn);
  cvtw_kernel<<<dim3(4096), dim3(256), 0, stream>>>(wkip, wvip, wk16, wv16);
  proj_gemm<<<dim3(32, 8, 2), dim3(256), 0, stream>>>(ipn, wk16, wv16, ipk, ipv);
  kv_build<<<dim3(32, 40), dim3(256), 0, stream>>>(k, v, ipk, ipv, w_k, w_ipk, Kcat, Vt);
  q_build<<<dim3(65536), dim3(128), 0, stream>>>(q, w_q, Qn);
  attn_kernel<<<dim3(1024), dim3(256), 0, stream>>>(Qn, Kcat, Vt, out);
}

// Round 3
// 422.758 us; speedup vs baseline: 2.0753x; 2.0753x over previous
//
#include <hip/hip_runtime.h>
#include <hip/hip_bf16.h>

typedef __attribute__((ext_vector_type(8))) __bf16 bf16x8;
typedef __attribute__((ext_vector_type(4))) float floatx4;

#define DEV static __device__ __forceinline__

typedef __attribute__((address_space(1))) const unsigned int gu32;
typedef __attribute__((address_space(3))) unsigned int lu32;

DEV void dma16(const void* g, void* l) {
  // async global->LDS, 16B/lane; LDS dst = wave-uniform base + lane*16
  __builtin_amdgcn_global_load_lds((gu32*)g, (lu32*)l, 16, 0, 0);
}

DEV unsigned short f2bf(float f) {
  unsigned int u = __float_as_uint(f);
  u += 0x7fffu + ((u >> 16) & 1u);   // round-to-nearest-even
  return (unsigned short)(u >> 16);
}

DEV float wred_sum(float v) {
#pragma unroll
  for (int o = 32; o > 0; o >>= 1) v += __shfl_xor(v, o, 64);
  return v;
}

// ---------------- K1: emb = silu(t_emb) @ W_ada^T + b_ada  -> [2][4096] f32
__global__ void ada_kernel(const float* __restrict__ t_emb, const float* __restrict__ W_ada,
                           const float* __restrict__ b_ada, float* __restrict__ emb) {
  int w = threadIdx.x >> 6, lane = threadIdx.x & 63;
  int gid = blockIdx.x * 4 + w;          // 0..8191
  int b = gid >> 12, n = gid & 4095;
  const float* te = t_emb + (size_t)b * 1280;
  const float* wr = W_ada + (size_t)n * 1280;
  float acc = 0.f;
#pragma unroll
  for (int i = 0; i < 20; ++i) {
    int t = lane + i * 64;
    float x = te[t];
    float s = x / (1.f + __expf(-x));
    acc += s * wr[t];
  }
  acc = wred_sum(acc);
  if (lane == 0) emb[gid] = acc + b_ada[n];
}

// ---------------- K2: LayerNorm(ip) * (1+scale) + shift -> bf16 ip_n [1024][2048]
__global__ void ln_mod_kernel(const float* __restrict__ ip, const float* __restrict__ emb,
                              unsigned short* __restrict__ ipn) {
  int row = blockIdx.x;            // b*512 + l
  int b = row >> 9;
  const float* x = ip + (size_t)row * 2048;
  float xv[8];
  float s1 = 0.f, s2 = 0.f;
#pragma unroll
  for (int i = 0; i < 8; ++i) {
    float v = x[threadIdx.x + i * 256];
    xv[i] = v; s1 += v; s2 += v * v;
  }
  s1 = wred_sum(s1); s2 = wred_sum(s2);
  __shared__ float r1[4], r2[4];
  int w = threadIdx.x >> 6, lane = threadIdx.x & 63;
  if (lane == 0) { r1[w] = s1; r2[w] = s2; }
  __syncthreads();
  s1 = r1[0] + r1[1] + r1[2] + r1[3];
  s2 = r2[0] + r2[1] + r2[2] + r2[3];
  float mu = s1 * (1.f / 2048.f);
  float var = s2 * (1.f / 2048.f) - mu * mu;
  float rs = rsqrtf(var + 1e-6f);
  const float* sh = emb + (size_t)b * 4096;
  unsigned short* y = ipn + (size_t)row * 2048;
#pragma unroll
  for (int i = 0; i < 8; ++i) {
    int d = threadIdx.x + i * 256;
    float v = (xv[i] - mu) * rs;
    v = v * (1.f + sh[2048 + d]) + sh[d];
    y[d] = f2bf(v);
  }
}

// ---------------- K3: convert W_k_ip / W_v_ip fp32 -> bf16
struct us4 { unsigned short a, b, c, d; };
__global__ void cvtw_kernel(const float* __restrict__ wk, const float* __restrict__ wv,
                            unsigned short* __restrict__ wk16, unsigned short* __restrict__ wv16) {
  size_t i = ((size_t)blockIdx.x * 256 + threadIdx.x) * 4;
  float4 a = *(const float4*)(wk + i);
  float4 b = *(const float4*)(wv + i);
  us4 oa = { f2bf(a.x), f2bf(a.y), f2bf(a.z), f2bf(a.w) };
  us4 ob = { f2bf(b.x), f2bf(b.y), f2bf(b.z), f2bf(b.w) };
  *(us4*)(wk16 + i) = oa;
  *(us4*)(wv16 + i) = ob;
}

// ---------------- K4: C[1024,2048] = A[1024,2048]bf16 @ W[2048,2048]^T bf16 -> f32
__global__ __launch_bounds__(256) void proj_gemm(const unsigned short* __restrict__ A,
    const unsigned short* __restrict__ Wk, const unsigned short* __restrict__ Wv,
    float* __restrict__ Ck, float* __restrict__ Cv) {
  const unsigned short* Bm = blockIdx.z ? Wv : Wk;
  float* C = blockIdx.z ? Cv : Ck;
  int n0 = blockIdx.x * 64, m0 = blockIdx.y * 128;
  __shared__ __align__(16) unsigned short As[128 * 72];
  __shared__ __align__(16) unsigned short Bs[64 * 72];
  int tid = threadIdx.x, w = tid >> 6, lane = tid & 63, quad = lane >> 4, l16 = lane & 15;
  floatx4 acc[2][4];
#pragma unroll
  for (int i = 0; i < 2; ++i)
#pragma unroll
    for (int j = 0; j < 4; ++j) { floatx4 z = {0.f, 0.f, 0.f, 0.f}; acc[i][j] = z; }
  for (int kk = 0; kk < 2048; kk += 64) {
#pragma unroll
    for (int it = 0; it < 4; ++it) {
      int idx = tid + it * 256;
      int row = idx >> 3, chk = idx & 7;
      *(uint4*)&As[row * 72 + chk * 8] = *(const uint4*)&A[(size_t)(m0 + row) * 2048 + kk + chk * 8];
    }
#pragma unroll
    for (int it = 0; it < 2; ++it) {
      int idx = tid + it * 256;
      int row = idx >> 3, chk = idx & 7;
      *(uint4*)&Bs[row * 72 + chk * 8] = *(const uint4*)&Bm[(size_t)(n0 + row) * 2048 + kk + chk * 8];
    }
    __syncthreads();
#pragma unroll
    for (int c = 0; c < 2; ++c) {
      bf16x8 a0 = *(const bf16x8*)&As[(w * 32 + l16) * 72 + quad * 8 + c * 32];
      bf16x8 a1 = *(const bf16x8*)&As[(w * 32 + 16 + l16) * 72 + quad * 8 + c * 32];
#pragma unroll
      for (int nt = 0; nt < 4; ++nt) {
        bf16x8 bb = *(const bf16x8*)&Bs[(nt * 16 + l16) * 72 + quad * 8 + c * 32];
        acc[0][nt] = __builtin_amdgcn_mfma_f32_16x16x32_bf16(a0, bb, acc[0][nt], 0, 0, 0);
        acc[1][nt] = __builtin_amdgcn_mfma_f32_16x16x32_bf16(a1, bb, acc[1][nt], 0, 0, 0);
      }
    }
    __syncthreads();
  }
#pragma unroll
  for (int rt = 0; rt < 2; ++rt)
#pragma unroll
    for (int nt = 0; nt < 4; ++nt)
#pragma unroll
      for (int r = 0; r < 4; ++r)
        C[(size_t)(m0 + w * 32 + rt * 16 + quad * 4 + r) * 2048 + n0 + nt * 16 + l16] = acc[rt][nt][r];
}

// ---------------- K5: Kcat [bh][2560][128] (rms, 16B-chunk XOR-swizzled per row)
//                      VtT  [bh][mt=40][128 d][64 m] (transposed tiles, XOR-swizzled)
__global__ __launch_bounds__(256) void kv_build(const float* __restrict__ img_key, const float* __restrict__ img_value,
                         const float* __restrict__ ipk, const float* __restrict__ ipv,
                         const float* __restrict__ w_k, const float* __restrict__ w_ipk,
                         unsigned short* __restrict__ Kc, unsigned short* __restrict__ VtT) {
  int bh = blockIdx.x;                 // 0..31
  int mt = blockIdx.y;                 // 0..39
  int b = bh >> 4, hh = bh & 15;
  int m0 = mt * 64;
  __shared__ __align__(16) unsigned short Vs[64 * 132];
  int tid = threadIdx.x;
  int mrow = tid >> 2, dq = tid & 3;   // 64 rows x 4 quarters of d
  int m = m0 + mrow;
  size_t base;
  const float* wsrc;
  const float *ksrc, *vsrc;
  if (m < 2048) {
    base = (size_t)(b * 2048 + m) * 2048 + hh * 128;
    ksrc = img_key + base; vsrc = img_value + base; wsrc = w_k;
  } else {
    base = (size_t)(b * 512 + (m - 2048)) * 2048 + hh * 128;
    ksrc = ipk + base; vsrc = ipv + base; wsrc = w_ipk;
  }
  // K: load 32 d-values, rms over 4 lanes sharing the row, write swizzled bf16
  float kvv[32]; float ss = 0.f;
  const float4* k4 = (const float4*)ksrc;
#pragma unroll
  for (int i = 0; i < 8; ++i) {
    float4 x = k4[dq * 8 + i];
    kvv[i * 4 + 0] = x.x; kvv[i * 4 + 1] = x.y; kvv[i * 4 + 2] = x.z; kvv[i * 4 + 3] = x.w;
    ss += x.x * x.x + x.y * x.y + x.z * x.z + x.w * x.w;
  }
  ss += __shfl_xor(ss, 1, 64);
  ss += __shfl_xor(ss, 2, 64);
  float rs = rsqrtf(ss * (1.f / 128.f) + 1e-6f);
  unsigned short kb[32];
#pragma unroll
  for (int j = 0; j < 32; ++j) kb[j] = f2bf(kvv[j] * rs * wsrc[dq * 32 + j]);
  uint4* kdst = (uint4*)&Kc[((size_t)bh * 2560 + m) * 128];
#pragma unroll
  for (int i = 0; i < 4; ++i) kdst[(dq * 4 + i) ^ (m & 7)] = ((const uint4*)kb)[i];
  // V: to LDS as bf16 [m][d] (stride 132), then transposed swizzled tile out
  const float4* v4 = (const float4*)vsrc;
#pragma unroll
  for (int i = 0; i < 8; ++i) {
    float4 x = v4[dq * 8 + i];
    us4 p = { f2bf(x.x), f2bf(x.y), f2bf(x.z), f2bf(x.w) };
    *(us4*)&Vs[mrow * 132 + dq * 32 + i * 4] = p;
  }
  __syncthreads();
  int d = tid >> 1, half = tid & 1;
  unsigned short ob[32];
#pragma unroll
  for (int j = 0; j < 32; ++j) ob[j] = Vs[(half * 32 + j) * 132 + d];
  uint4* vdst = (uint4*)&VtT[((size_t)(bh * 40 + mt)) * 8192 + d * 64];
#pragma unroll
  for (int i = 0; i < 4; ++i) vdst[(half * 4 + i) ^ (d & 7)] = ((const uint4*)ob)[i];
}

// ---------------- K6: Qn [B,H,2048,128] bf16 with rms. One block = one (b,l) row.
__global__ __launch_bounds__(256) void q_build(const float* __restrict__ img_query, const float* __restrict__ w_q,
                        unsigned short* __restrict__ Qn) {
  int row = blockIdx.x;                       // b*2048 + l
  int b = row >> 11, l = row & 2047;
  int t = threadIdx.x;
  const float4* src = (const float4*)(img_query + (size_t)row * 2048);
  float4 x0 = src[t * 2], x1 = src[t * 2 + 1];
  float ss = x0.x * x0.x + x0.y * x0.y + x0.z * x0.z + x0.w * x0.w
           + x1.x * x1.x + x1.y * x1.y + x1.z * x1.z + x1.w * x1.w;
  // lanes t with same t>>4 form contiguous 16-lane groups within a wave
  ss += __shfl_xor(ss, 1, 64); ss += __shfl_xor(ss, 2, 64);
  ss += __shfl_xor(ss, 4, 64); ss += __shfl_xor(ss, 8, 64);
  float rs = rsqrtf(ss * (1.f / 128.f) + 1e-6f);
  int h = t >> 4, d0 = (t & 15) * 8;
  const float* wq = w_q + d0;
  float xs[8] = { x0.x, x0.y, x0.z, x0.w, x1.x, x1.y, x1.z, x1.w };
  unsigned short ob[8];
#pragma unroll
  for (int j = 0; j < 8; ++j) ob[j] = f2bf(xs[j] * rs * wq[j]);
  *(uint4*)&Qn[((size_t)(b * 16 + h) * 2048 + l) * 128 + d0] = *(const uint4*)ob;
}

// ---------------- K7: flash attention, m97-style async-staged K-loop.
// K tile [64][128] + V^T tile [128][64] staged via global_load_lds (swizzle
// pre-baked into the global layouts so the contiguous DMA lands conflict-free);
// fixed-max softmax; per-wave P roundtrip (LDS, XOR-swizzled, stride 64).
// LDS = 16+16+8 = 40KB -> 4 blocks/CU.
__global__ __launch_bounds__(256, 4) void attn_kernel(const unsigned short* __restrict__ Qn,
    const unsigned short* __restrict__ Kc, const unsigned short* __restrict__ VtT,
    float* __restrict__ out) {
  const float SCL = 0.12751744f;   // (1/sqrt(128)) * log2(e)
  const float FM = 17.0f;          // fixed softmax max (score*SCL bounded by 16.4)
  int bh = blockIdx.x & 31;        // bh fastest -> each XCD sees ~4 bh's K/V in its L2
  int qt = blockIdx.x >> 5;
  int b = bh >> 4, hh = bh & 15;
  int tid = threadIdx.x, w = tid >> 6, lane = tid & 63, quad = lane >> 4, l16 = lane & 15;

  __shared__ __align__(16) unsigned short Kt[64 * 128];
  __shared__ __align__(16) unsigned short Vs[128 * 64];
  __shared__ __align__(16) unsigned short Pt[4 * 16 * 64];
  unsigned short* Pw = Pt + w * (16 * 64);

  int q0 = qt * 64;
  const unsigned short* Qbase = Qn + ((size_t)bh * 2048 + q0) * 128;
  const unsigned short* Kb = Kc + (size_t)bh * 2560 * 128;
  const unsigned short* Vb = VtT + (size_t)bh * 40 * 8192;

  bf16x8 aq[4];
  {
    int qrow = w * 16 + l16;
#pragma unroll
    for (int c = 0; c < 4; ++c)
      aq[c] = *(const bf16x8*)&Qbase[(size_t)qrow * 128 + quad * 8 + c * 32];
  }

  floatx4 acc[8];
#pragma unroll
  for (int i = 0; i < 8; ++i) { floatx4 z = {0.f, 0.f, 0.f, 0.f}; acc[i] = z; }
  float rsum[4] = {0.f, 0.f, 0.f, 0.f};

  int xr = l16 & 7;                      // XOR key for B-frag rows (row&7 == l16&7)
  for (int t = 0; t < 40; ++t) {
    const unsigned short* Ksrc = Kb + (size_t)t * 8192;
    const unsigned short* Vsrc = Vb + (size_t)t * 8192;
    int seg = w * 4;
#pragma unroll
    for (int j = 0; j < 4; ++j) {
      int off = (seg + j) * 512 + lane * 8;
      dma16(Ksrc + off, &Kt[(seg + j) * 512]);
      dma16(Vsrc + off, &Vs[(seg + j) * 512]);
    }
    __syncthreads();

    // S = Q K^T : B-frag row nt*16+l16, logical chunk quad+c*4, phys = chunk^xr
    floatx4 s[4];
#pragma unroll
    for (int nt = 0; nt < 4; ++nt) {
      floatx4 z = {0.f, 0.f, 0.f, 0.f}; s[nt] = z;
#pragma unroll
      for (int c = 0; c < 4; ++c) {
        bf16x8 bk = *(const bf16x8*)&Kt[(nt * 16 + l16) * 128 + ((quad + c * 4) ^ xr) * 8];
        s[nt] = __builtin_amdgcn_mfma_f32_16x16x32_bf16(aq[c], bk, s[nt], 0, 0, 0);
      }
    }
    // P = exp2(s*SCL - FM); per-lane partial row sums
#pragma unroll
    for (int nt = 0; nt < 4; ++nt)
#pragma unroll
      for (int r = 0; r < 4; ++r) {
        float p = exp2f(s[nt][r] * SCL - FM);
        rsum[r] += p;
        int qr = quad * 4 + r;
        int chk = nt * 2 + (l16 >> 3);
        Pw[qr * 64 + ((chk ^ (qr & 7)) * 8) + (l16 & 7)] = f2bf(p);
      }
    // A-frag of P: row l16, chunks quad and quad+4, phys = chunk^(l16&7)
    bf16x8 ap0 = *(const bf16x8*)&Pw[l16 * 64 + ((quad ^ xr) * 8)];
    bf16x8 ap1 = *(const bf16x8*)&Pw[l16 * 64 + (((quad + 4) ^ xr) * 8)];
    // O += P V : B-frag row (d) nt*16+l16, chunks quad / quad+4 over m
#pragma unroll
    for (int nt = 0; nt < 8; ++nt) {
      bf16x8 bv0 = *(const bf16x8*)&Vs[(nt * 16 + l16) * 64 + ((quad ^ xr) * 8)];
      bf16x8 bv1 = *(const bf16x8*)&Vs[(nt * 16 + l16) * 64 + (((quad + 4) ^ xr) * 8)];
      acc[nt] = __builtin_amdgcn_mfma_f32_16x16x32_bf16(ap0, bv0, acc[nt], 0, 0, 0);
      acc[nt] = __builtin_amdgcn_mfma_f32_16x16x32_bf16(ap1, bv1, acc[nt], 0, 0, 0);
    }
    __syncthreads();
  }
  // final row-sum across the 16 l16 lanes
#pragma unroll
  for (int r = 0; r < 4; ++r) {
#pragma unroll
    for (int o = 1; o < 16; o <<= 1) rsum[r] += __shfl_xor(rsum[r], o, 64);
  }
  float inv[4];
#pragma unroll
  for (int r = 0; r < 4; ++r) inv[r] = 1.f / rsum[r];
#pragma unroll
  for (int nt = 0; nt < 8; ++nt)
#pragma unroll
    for (int r = 0; r < 4; ++r) {
      int qrow = q0 + w * 16 + quad * 4 + r;
      out[((size_t)(b * 2048 + qrow)) * 2048 + hh * 128 + nt * 16 + l16] = acc[nt][r] * inv[r];
    }
}

extern "C" void kernel_launch(void* const* d_in, const int* in_sizes, int n_in,
                              void* d_out, int out_size, void* d_ws, size_t ws_size,
                              hipStream_t stream) {
  const float* ip    = (const float*)d_in[0];
  const float* q     = (const float*)d_in[1];
  const float* k     = (const float*)d_in[2];
  const float* v     = (const float*)d_in[3];
  const float* temb  = (const float*)d_in[4];
  const float* wada  = (const float*)d_in[5];
  const float* bada  = (const float*)d_in[6];
  const float* wkip  = (const float*)d_in[7];
  const float* wvip  = (const float*)d_in[8];
  const float* w_q   = (const float*)d_in[9];
  const float* w_k   = (const float*)d_in[10];
  const float* w_ipk = (const float*)d_in[11];
  float* out = (float*)d_out;
  char* ws = (char*)d_ws;

  // Lifetime-overlapped workspace layout (75.5 MB total):
  //   emb[0,32K) ipn[32K,4.2M) wk16[4.2M,12.6M) wv16[12.6M,21.0M)  (dead after proj_gemm)
  //   Qn[0,16.7M) Kcat[16.7M,37.7M) VtT[37.7M,58.7M)               (written after proj_gemm)
  //   ipk[58.7M,67.1M) ipv[67.1M,75.5M)
  float* emb           = (float*)(ws + 0);
  unsigned short* ipn  = (unsigned short*)(ws + 32768);
  unsigned short* wk16 = (unsigned short*)(ws + 4227072);
  unsigned short* wv16 = (unsigned short*)(ws + 12615680);
  unsigned short* Qn   = (unsigned short*)(ws + 0);
  unsigned short* Kcat = (unsigned short*)(ws + 16777216);
  unsigned short* VtT  = (unsigned short*)(ws + 37748736);
  float* ipk           = (float*)(ws + 58720256);
  float* ipv           = (float*)(ws + 67108864);

  ada_kernel<<<dim3(2048), dim3(256), 0, stream>>>(temb, wada, bada, emb);
  ln_mod_kernel<<<dim3(1024), dim3(256), 0, stream>>>(ip, emb, ipn);
  cvtw_kernel<<<dim3(4096), dim3(256), 0, stream>>>(wkip, wvip, wk16, wv16);
  proj_gemm<<<dim3(32, 8, 2), dim3(256), 0, stream>>>(ipn, wk16, wv16, ipk, ipv);
  kv_build<<<dim3(32, 40), dim3(256), 0, stream>>>(k, v, ipk, ipv, w_k, w_ipk, Kcat, VtT);
  q_build<<<dim3(4096), dim3(256), 0, stream>>>(q, w_q, Qn);
  attn_kernel<<<dim3(1024), dim3(256), 0, stream>>>(Qn, Kcat, VtT, out);
}

// Round 4
// 412.317 us; speedup vs baseline: 2.1279x; 1.0253x over previous
//
#include <hip/hip_runtime.h>
#include <hip/hip_bf16.h>

typedef __attribute__((ext_vector_type(8))) __bf16 bf16x8;
typedef __attribute__((ext_vector_type(2))) __bf16 bf16x2;
typedef __attribute__((ext_vector_type(4))) float floatx4;
typedef __attribute__((ext_vector_type(4))) short short4v;

#define DEV static __device__ __forceinline__

typedef __attribute__((address_space(1))) const unsigned int gu32;
typedef __attribute__((address_space(3))) unsigned int lu32;

DEV void dma16(const void* g, void* l) {
  // async global->LDS, 16B/lane; LDS dst = wave-uniform base + lane*16
  __builtin_amdgcn_global_load_lds((gu32*)g, (lu32*)l, 16, 0, 0);
}

DEV unsigned short f2bf(float f) {
  unsigned int u = __float_as_uint(f);
  u += 0x7fffu + ((u >> 16) & 1u);   // round-to-nearest-even
  return (unsigned short)(u >> 16);
}

DEV unsigned int pk_bf16(float a, float b) {
#if __has_builtin(__builtin_amdgcn_cvt_pk_bf16_f32)
  bf16x2 r = __builtin_amdgcn_cvt_pk_bf16_f32(a, b);
  union { bf16x2 v; unsigned int u; } c; c.v = r;
  return c.u;
#else
  return (unsigned int)f2bf(a) | ((unsigned int)f2bf(b) << 16);
#endif
}

DEV float wred_sum(float v) {
#pragma unroll
  for (int o = 32; o > 0; o >>= 1) v += __shfl_xor(v, o, 64);
  return v;
}

DEV floatx4 mfma32(bf16x8 a, bf16x8 b, floatx4 c) {
  return __builtin_amdgcn_mfma_f32_16x16x32_bf16(a, b, c, 0, 0, 0);
}
DEV floatx4 mfma16(short4v a, short4v b, floatx4 c) {
  return __builtin_amdgcn_mfma_f32_16x16x16bf16_1k(a, b, c, 0, 0, 0);
}

// ---------------- K1: emb = silu(t_emb) @ W_ada^T + b_ada  -> [2][4096] f32
__global__ void ada_kernel(const float* __restrict__ t_emb, const float* __restrict__ W_ada,
                           const float* __restrict__ b_ada, float* __restrict__ emb) {
  int w = threadIdx.x >> 6, lane = threadIdx.x & 63;
  int gid = blockIdx.x * 4 + w;          // 0..8191
  int b = gid >> 12, n = gid & 4095;
  const float* te = t_emb + (size_t)b * 1280;
  const float* wr = W_ada + (size_t)n * 1280;
  float acc = 0.f;
#pragma unroll
  for (int i = 0; i < 20; ++i) {
    int t = lane + i * 64;
    float x = te[t];
    float s = x / (1.f + __expf(-x));
    acc += s * wr[t];
  }
  acc = wred_sum(acc);
  if (lane == 0) emb[gid] = acc + b_ada[n];
}

// ---------------- K2: LayerNorm(ip) * (1+scale) + shift -> bf16 ip_n [1024][2048]
__global__ void ln_mod_kernel(const float* __restrict__ ip, const float* __restrict__ emb,
                              unsigned short* __restrict__ ipn) {
  int row = blockIdx.x;            // b*512 + l
  int b = row >> 9;
  const float* x = ip + (size_t)row * 2048;
  float xv[8];
  float s1 = 0.f, s2 = 0.f;
#pragma unroll
  for (int i = 0; i < 8; ++i) {
    float v = x[threadIdx.x + i * 256];
    xv[i] = v; s1 += v; s2 += v * v;
  }
  s1 = wred_sum(s1); s2 = wred_sum(s2);
  __shared__ float r1[4], r2[4];
  int w = threadIdx.x >> 6, lane = threadIdx.x & 63;
  if (lane == 0) { r1[w] = s1; r2[w] = s2; }
  __syncthreads();
  s1 = r1[0] + r1[1] + r1[2] + r1[3];
  s2 = r2[0] + r2[1] + r2[2] + r2[3];
  float mu = s1 * (1.f / 2048.f);
  float var = s2 * (1.f / 2048.f) - mu * mu;
  float rs = rsqrtf(var + 1e-6f);
  const float* sh = emb + (size_t)b * 4096;
  unsigned short* y = ipn + (size_t)row * 2048;
#pragma unroll
  for (int i = 0; i < 8; ++i) {
    int d = threadIdx.x + i * 256;
    float v = (xv[i] - mu) * rs;
    v = v * (1.f + sh[2048 + d]) + sh[d];
    y[d] = f2bf(v);
  }
}

// ---------------- K3: convert W_k_ip / W_v_ip fp32 -> bf16
struct us4 { unsigned short a, b, c, d; };
__global__ void cvtw_kernel(const float* __restrict__ wk, const float* __restrict__ wv,
                            unsigned short* __restrict__ wk16, unsigned short* __restrict__ wv16) {
  size_t i = ((size_t)blockIdx.x * 256 + threadIdx.x) * 4;
  float4 a = *(const float4*)(wk + i);
  float4 b = *(const float4*)(wv + i);
  us4 oa = { f2bf(a.x), f2bf(a.y), f2bf(a.z), f2bf(a.w) };
  us4 ob = { f2bf(b.x), f2bf(b.y), f2bf(b.z), f2bf(b.w) };
  *(us4*)(wk16 + i) = oa;
  *(us4*)(wv16 + i) = ob;
}

// ---------------- K4: C[1024,2048] = A[1024,2048]bf16 @ W[2048,2048]^T bf16 -> f32
__global__ __launch_bounds__(256) void proj_gemm(const unsigned short* __restrict__ A,
    const unsigned short* __restrict__ Wk, const unsigned short* __restrict__ Wv,
    float* __restrict__ Ck, float* __restrict__ Cv) {
  const unsigned short* Bm = blockIdx.z ? Wv : Wk;
  float* C = blockIdx.z ? Cv : Ck;
  int n0 = blockIdx.x * 64, m0 = blockIdx.y * 128;
  __shared__ __align__(16) unsigned short As[128 * 72];
  __shared__ __align__(16) unsigned short Bs[64 * 72];
  int tid = threadIdx.x, w = tid >> 6, lane = tid & 63, quad = lane >> 4, l16 = lane & 15;
  floatx4 acc[2][4];
#pragma unroll
  for (int i = 0; i < 2; ++i)
#pragma unroll
    for (int j = 0; j < 4; ++j) { floatx4 z = {0.f, 0.f, 0.f, 0.f}; acc[i][j] = z; }
  for (int kk = 0; kk < 2048; kk += 64) {
#pragma unroll
    for (int it = 0; it < 4; ++it) {
      int idx = tid + it * 256;
      int row = idx >> 3, chk = idx & 7;
      *(uint4*)&As[row * 72 + chk * 8] = *(const uint4*)&A[(size_t)(m0 + row) * 2048 + kk + chk * 8];
    }
#pragma unroll
    for (int it = 0; it < 2; ++it) {
      int idx = tid + it * 256;
      int row = idx >> 3, chk = idx & 7;
      *(uint4*)&Bs[row * 72 + chk * 8] = *(const uint4*)&Bm[(size_t)(n0 + row) * 2048 + kk + chk * 8];
    }
    __syncthreads();
#pragma unroll
    for (int c = 0; c < 2; ++c) {
      bf16x8 a0 = *(const bf16x8*)&As[(w * 32 + l16) * 72 + quad * 8 + c * 32];
      bf16x8 a1 = *(const bf16x8*)&As[(w * 32 + 16 + l16) * 72 + quad * 8 + c * 32];
#pragma unroll
      for (int nt = 0; nt < 4; ++nt) {
        bf16x8 bb = *(const bf16x8*)&Bs[(nt * 16 + l16) * 72 + quad * 8 + c * 32];
        acc[0][nt] = mfma32(a0, bb, acc[0][nt]);
        acc[1][nt] = mfma32(a1, bb, acc[1][nt]);
      }
    }
    __syncthreads();
  }
#pragma unroll
  for (int rt = 0; rt < 2; ++rt)
#pragma unroll
    for (int nt = 0; nt < 4; ++nt)
#pragma unroll
      for (int r = 0; r < 4; ++r)
        C[(size_t)(m0 + w * 32 + rt * 16 + quad * 4 + r) * 2048 + n0 + nt * 16 + l16] = acc[rt][nt][r];
}

// ---------------- K5: Kcat [bh][2560][128] (rms, 16B-chunk XOR-swizzled per row)
//                      VtT  [bh][mt=40][128 d][64 m] (transposed tiles, XOR-swizzled)
__global__ __launch_bounds__(256) void kv_build(const float* __restrict__ img_key, const float* __restrict__ img_value,
                         const float* __restrict__ ipk, const float* __restrict__ ipv,
                         const float* __restrict__ w_k, const float* __restrict__ w_ipk,
                         unsigned short* __restrict__ Kc, unsigned short* __restrict__ VtT) {
  int bh = blockIdx.x;                 // 0..31
  int mt = blockIdx.y;                 // 0..39
  int b = bh >> 4, hh = bh & 15;
  int m0 = mt * 64;
  __shared__ __align__(16) unsigned short Vs[64 * 132];
  int tid = threadIdx.x;
  int mrow = tid >> 2, dq = tid & 3;   // 64 rows x 4 quarters of d
  int m = m0 + mrow;
  size_t base;
  const float* wsrc;
  const float *ksrc, *vsrc;
  if (m < 2048) {
    base = (size_t)(b * 2048 + m) * 2048 + hh * 128;
    ksrc = img_key + base; vsrc = img_value + base; wsrc = w_k;
  } else {
    base = (size_t)(b * 512 + (m - 2048)) * 2048 + hh * 128;
    ksrc = ipk + base; vsrc = ipv + base; wsrc = w_ipk;
  }
  // K: load 32 d-values, rms over 4 lanes sharing the row, write swizzled bf16
  float kvv[32]; float ss = 0.f;
  const float4* k4 = (const float4*)ksrc;
#pragma unroll
  for (int i = 0; i < 8; ++i) {
    float4 x = k4[dq * 8 + i];
    kvv[i * 4 + 0] = x.x; kvv[i * 4 + 1] = x.y; kvv[i * 4 + 2] = x.z; kvv[i * 4 + 3] = x.w;
    ss += x.x * x.x + x.y * x.y + x.z * x.z + x.w * x.w;
  }
  ss += __shfl_xor(ss, 1, 64);
  ss += __shfl_xor(ss, 2, 64);
  float rs = rsqrtf(ss * (1.f / 128.f) + 1e-6f);
  unsigned short kb[32];
#pragma unroll
  for (int j = 0; j < 32; ++j) kb[j] = f2bf(kvv[j] * rs * wsrc[dq * 32 + j]);
  uint4* kdst = (uint4*)&Kc[((size_t)bh * 2560 + m) * 128];
#pragma unroll
  for (int i = 0; i < 4; ++i) kdst[(dq * 4 + i) ^ (m & 7)] = ((const uint4*)kb)[i];
  // V: to LDS as bf16 [m][d] (stride 132), then transposed swizzled tile out
  const float4* v4 = (const float4*)vsrc;
#pragma unroll
  for (int i = 0; i < 8; ++i) {
    float4 x = v4[dq * 8 + i];
    us4 p = { f2bf(x.x), f2bf(x.y), f2bf(x.z), f2bf(x.w) };
    *(us4*)&Vs[mrow * 132 + dq * 32 + i * 4] = p;
  }
  __syncthreads();
  int d = tid >> 1, half = tid & 1;
  unsigned short ob[32];
#pragma unroll
  for (int j = 0; j < 32; ++j) ob[j] = Vs[(half * 32 + j) * 132 + d];
  uint4* vdst = (uint4*)&VtT[((size_t)(bh * 40 + mt)) * 8192 + d * 64];
#pragma unroll
  for (int i = 0; i < 4; ++i) vdst[(half * 4 + i) ^ (d & 7)] = ((const uint4*)ob)[i];
}

// ---------------- K7: flash attention, transposed-S formulation.
// S^T = K·Q^T (A=K-frag from LDS, B=Q-frag in regs) -> P in registers is
// directly the B-frag of mfma_16x16x16 -> PV = V^T·P with A=V^T (b64 LDS
// reads). No P roundtrip. Waves split 2D: qh = q-half (32 q), mh = m-half
// (32 m of each 64-tile); fixed-max softmax makes the m-split reduction a
// single epilogue add. Q RMS-norm fused (reads f32 img_query directly).
__global__ __launch_bounds__(256, 3) void attn_kernel(const float* __restrict__ Qf,
    const float* __restrict__ w_q,
    const unsigned short* __restrict__ Kc, const unsigned short* __restrict__ VtT,
    float* __restrict__ out) {
  const float SCL = 0.12751744f;   // (1/sqrt(128)) * log2(e)
  const float FM = 17.0f;          // fixed softmax max (score*SCL bounded by 16.4)
  int bh = blockIdx.x & 31;        // bh fastest -> XCD L2 locality on K/V
  int qt = blockIdx.x >> 5;        // 0..31
  int b = bh >> 4, hh = bh & 15;
  int tid = threadIdx.x, w = tid >> 6, lane = tid & 63, quad = lane >> 4, l16 = lane & 15;
  int qh = w >> 1, mh = w & 1;
  int xr = l16 & 7;

  __shared__ __align__(16) unsigned char smem[34048];    // staging 32KB | epi 64x132 f32
  unsigned short* Kt = (unsigned short*)smem;            // [64 m][128 d], swizzled
  unsigned short* Vs = (unsigned short*)(smem + 16384);  // [128 d][64 m], swizzled
  float* epi = (float*)smem;                             // [64 q][132]
  __shared__ float rsl[4][32];

  int q0 = qt * 64;

  // ---- Q: load f32, RMS-norm, pack to A/B bf16 fragments (2 q-tiles/wave)
  bf16x8 aq[2][4];
#pragma unroll
  for (int qtl = 0; qtl < 2; ++qtl) {
    int qrow = q0 + qh * 32 + qtl * 16 + l16;
    const float* src = Qf + ((size_t)(b * 2048 + qrow)) * 2048 + hh * 128;
    float xs[32]; float ss = 0.f;
#pragma unroll
    for (int c = 0; c < 4; ++c) {
      float4 a = *(const float4*)&src[quad * 8 + c * 32];
      float4 b2 = *(const float4*)&src[quad * 8 + c * 32 + 4];
      xs[c * 8 + 0] = a.x;  xs[c * 8 + 1] = a.y;  xs[c * 8 + 2] = a.z;  xs[c * 8 + 3] = a.w;
      xs[c * 8 + 4] = b2.x; xs[c * 8 + 5] = b2.y; xs[c * 8 + 6] = b2.z; xs[c * 8 + 7] = b2.w;
      ss += a.x * a.x + a.y * a.y + a.z * a.z + a.w * a.w
          + b2.x * b2.x + b2.y * b2.y + b2.z * b2.z + b2.w * b2.w;
    }
    ss += __shfl_xor(ss, 16, 64);
    ss += __shfl_xor(ss, 32, 64);
    float rs = rsqrtf(ss * (1.f / 128.f) + 1e-6f);
#pragma unroll
    for (int c = 0; c < 4; ++c) {
      float4 wa = *(const float4*)&w_q[quad * 8 + c * 32];
      float4 wb = *(const float4*)&w_q[quad * 8 + c * 32 + 4];
      union { unsigned int u[4]; bf16x8 v; } pk;
      pk.u[0] = pk_bf16(xs[c * 8 + 0] * rs * wa.x, xs[c * 8 + 1] * rs * wa.y);
      pk.u[1] = pk_bf16(xs[c * 8 + 2] * rs * wa.z, xs[c * 8 + 3] * rs * wa.w);
      pk.u[2] = pk_bf16(xs[c * 8 + 4] * rs * wb.x, xs[c * 8 + 5] * rs * wb.y);
      pk.u[3] = pk_bf16(xs[c * 8 + 6] * rs * wb.z, xs[c * 8 + 7] * rs * wb.w);
      aq[qtl][c] = pk.v;
    }
  }

  const unsigned short* Kb = Kc + (size_t)bh * 2560 * 128;
  const unsigned short* Vb = VtT + (size_t)bh * 40 * 8192;

  floatx4 acc[2][8];
#pragma unroll
  for (int i = 0; i < 2; ++i)
#pragma unroll
    for (int j = 0; j < 8; ++j) { floatx4 z = {0.f, 0.f, 0.f, 0.f}; acc[i][j] = z; }
  float rsum[2] = {0.f, 0.f};

  for (int t = 0; t < 40; ++t) {
    const unsigned short* Ksrc = Kb + (size_t)t * 8192;
    const unsigned short* Vsrc = Vb + (size_t)t * 8192;
    int seg = w * 4;
#pragma unroll
    for (int j = 0; j < 4; ++j) {
      int off = (seg + j) * 512 + lane * 8;
      dma16(Ksrc + off, Kt + (seg + j) * 512);
      dma16(Vsrc + off, Vs + (seg + j) * 512);
    }
    __syncthreads();

    // S^T = K·Q^T for this wave's 2 m-tiles x 2 q-tiles, then P in registers
    short4v pb[2][2];
#pragma unroll
    for (int nt2 = 0; nt2 < 2; ++nt2) {
      floatx4 s0 = {0.f, 0.f, 0.f, 0.f}, s1 = {0.f, 0.f, 0.f, 0.f};
      int krow = (mh * 32 + nt2 * 16 + l16) * 128;
#pragma unroll
      for (int c = 0; c < 4; ++c) {
        bf16x8 bk = *(const bf16x8*)&Kt[krow + ((quad + c * 4) ^ xr) * 8];
        s0 = mfma32(bk, aq[0][c], s0);
        s1 = mfma32(bk, aq[1][c], s1);
      }
      float p0 = __builtin_amdgcn_exp2f(fmaf(s0[0], SCL, -FM));
      float p1 = __builtin_amdgcn_exp2f(fmaf(s0[1], SCL, -FM));
      float p2 = __builtin_amdgcn_exp2f(fmaf(s0[2], SCL, -FM));
      float p3 = __builtin_amdgcn_exp2f(fmaf(s0[3], SCL, -FM));
      rsum[0] += (p0 + p1) + (p2 + p3);
      union { unsigned int u[2]; short4v v; } pa;
      pa.u[0] = pk_bf16(p0, p1); pa.u[1] = pk_bf16(p2, p3);
      pb[nt2][0] = pa.v;
      p0 = __builtin_amdgcn_exp2f(fmaf(s1[0], SCL, -FM));
      p1 = __builtin_amdgcn_exp2f(fmaf(s1[1], SCL, -FM));
      p2 = __builtin_amdgcn_exp2f(fmaf(s1[2], SCL, -FM));
      p3 = __builtin_amdgcn_exp2f(fmaf(s1[3], SCL, -FM));
      rsum[1] += (p0 + p1) + (p2 + p3);
      pa.u[0] = pk_bf16(p0, p1); pa.u[1] = pk_bf16(p2, p3);
      pb[nt2][1] = pa.v;
    }

    // O^T += V^T·P : A-frag = V^T b64 reads (shared across q-tiles)
#pragma unroll
    for (int dt = 0; dt < 8; ++dt) {
      int vrow = (dt * 16 + l16) * 64;
#pragma unroll
      for (int nt2 = 0; nt2 < 2; ++nt2) {
        int mcg = mh * 2 + nt2;
        union { uint2 u; short4v v; } va;
        va.u = *(const uint2*)&Vs[vrow + (((mcg * 2 + (quad >> 1)) ^ xr) * 8) + (quad & 1) * 4];
        acc[0][dt] = mfma16(va.v, pb[nt2][0], acc[0][dt]);
        acc[1][dt] = mfma16(va.v, pb[nt2][1], acc[1][dt]);
      }
    }
    __syncthreads();
  }

  // ---- epilogue: reduce rsum across quads; sum m-half partials via LDS
  rsum[0] += __shfl_xor(rsum[0], 16, 64); rsum[0] += __shfl_xor(rsum[0], 32, 64);
  rsum[1] += __shfl_xor(rsum[1], 16, 64); rsum[1] += __shfl_xor(rsum[1], 32, 64);
  if (quad == 0) { rsl[w][l16] = rsum[0]; rsl[w][16 + l16] = rsum[1]; }
  if (mh == 1) {
#pragma unroll
    for (int qtl = 0; qtl < 2; ++qtl)
#pragma unroll
      for (int dt = 0; dt < 8; ++dt)
        *(floatx4*)&epi[(qh * 32 + qtl * 16 + l16) * 132 + dt * 16 + quad * 4] = acc[qtl][dt];
  }
  __syncthreads();
  if (mh == 0) {
#pragma unroll
    for (int qtl = 0; qtl < 2; ++qtl) {
      float inv = 1.f / (rsum[qtl] + rsl[w + 1][qtl * 16 + l16]);
      int qrow = q0 + qh * 32 + qtl * 16 + l16;
      float* orow = out + ((size_t)(b * 2048 + qrow)) * 2048 + hh * 128;
#pragma unroll
      for (int dt = 0; dt < 8; ++dt) {
        floatx4 part = *(const floatx4*)&epi[(qh * 32 + qtl * 16 + l16) * 132 + dt * 16 + quad * 4];
        floatx4 r = (acc[qtl][dt] + part) * inv;
        *(floatx4*)&orow[dt * 16 + quad * 4] = r;
      }
    }
  }
}

extern "C" void kernel_launch(void* const* d_in, const int* in_sizes, int n_in,
                              void* d_out, int out_size, void* d_ws, size_t ws_size,
                              hipStream_t stream) {
  const float* ip    = (const float*)d_in[0];
  const float* q     = (const float*)d_in[1];
  const float* k     = (const float*)d_in[2];
  const float* v     = (const float*)d_in[3];
  const float* temb  = (const float*)d_in[4];
  const float* wada  = (const float*)d_in[5];
  const float* bada  = (const float*)d_in[6];
  const float* wkip  = (const float*)d_in[7];
  const float* wvip  = (const float*)d_in[8];
  const float* w_q   = (const float*)d_in[9];
  const float* w_k   = (const float*)d_in[10];
  const float* w_ipk = (const float*)d_in[11];
  float* out = (float*)d_out;
  char* ws = (char*)d_ws;

  // Lifetime-overlapped workspace layout (75.5 MB total):
  //   emb[0,32K) ipn[32K,4.2M) wk16[4.2M,12.6M) wv16[12.6M,21.0M)  (dead after proj_gemm)
  //   Kcat[16.7M,37.7M) VtT[37.7M,58.7M)
  //   ipk[58.7M,67.1M) ipv[67.1M,75.5M)
  float* emb           = (float*)(ws + 0);
  unsigned short* ipn  = (unsigned short*)(ws + 32768);
  unsigned short* wk16 = (unsigned short*)(ws + 4227072);
  unsigned short* wv16 = (unsigned short*)(ws + 12615680);
  unsigned short* Kcat = (unsigned short*)(ws + 16777216);
  unsigned short* VtT  = (unsigned short*)(ws + 37748736);
  float* ipk           = (float*)(ws + 58720256);
  float* ipv           = (float*)(ws + 67108864);

  ada_kernel<<<dim3(2048), dim3(256), 0, stream>>>(temb, wada, bada, emb);
  ln_mod_kernel<<<dim3(1024), dim3(256), 0, stream>>>(ip, emb, ipn);
  cvtw_kernel<<<dim3(4096), dim3(256), 0, stream>>>(wkip, wvip, wk16, wv16);
  proj_gemm<<<dim3(32, 8, 2), dim3(256), 0, stream>>>(ipn, wk16, wv16, ipk, ipv);
  kv_build<<<dim3(32, 40), dim3(256), 0, stream>>>(k, v, ipk, ipv, w_k, w_ipk, Kcat, VtT);
  attn_kernel<<<dim3(1024), dim3(256), 0, stream>>>(q, w_q, Kcat, VtT, out);
}